// Round 1
// baseline (332.261 us; speedup 1.0000x reference)
//
#include <hip/hip_runtime.h>

// Problem constants
#define CC   128      // input channels
#define SB   16384    // T*H*W per batch
#define NB   8        // batch

typedef _Float16 half4_t __attribute__((ext_vector_type(4)));
typedef _Float16 half2_t __attribute__((ext_vector_type(2)));

// workspace byte offsets (total use: 50,598,912 bytes)
#define WT_OFF    0u          // 24576 floats, WT[c*192 + slot] (phi|theta|rho)
#define BIAS_OFF  98304u      // 192 floats
#define CM_OFF    99072u      // 8*1024 floats
#define SUME_OFF  131840u     // 512 floats
#define RINV_OFF  133888u     // 512 floats
#define ABT_OFF   135936u     // 8*4096 floats, ABt[b][n][m]
#define E_OFF     267264u     // 8*64*16384 halves  exp(theta)
#define V_OFF     17044480u   // 8*64*16384 halves  V (softmax over channels)
#define PART_OFF  33821696u   // 1024*4096 floats   per-block AB partials

// ---------------------------------------------------------------- k0: setup
__global__ void k0_setup(const float* __restrict__ cond,
                         const float* __restrict__ W_phi, const float* __restrict__ b_phi,
                         const float* __restrict__ W_theta, const float* __restrict__ b_theta,
                         const float* __restrict__ W_rho, const float* __restrict__ b_rho,
                         const float* __restrict__ W1, const float* __restrict__ b1,
                         const float* __restrict__ W2, const float* __restrict__ b2,
                         char* __restrict__ wsc) {
  __shared__ float sc[64], sh1[64], red[256];
  int t = threadIdx.x, bid = blockIdx.x;
  if (bid < 8) {
    // Cm for batch b: h1=relu(cond@W1^T+b1); h2=relu(h1@W2^T+b2); softmax(h2)
    int b = bid;
    if (t < 64) sc[t] = cond[b*64 + t];
    __syncthreads();
    if (t < 64) {
      float acc = b1[t];
      for (int k = 0; k < 64; ++k) acc += sc[k] * W1[t*64 + k];
      sh1[t] = fmaxf(acc, 0.f);
    }
    __syncthreads();
    float ev[4]; float ps = 0.f;
    #pragma unroll
    for (int q = 0; q < 4; ++q) {
      int o = q*256 + t;
      float acc = b2[o];
      for (int k = 0; k < 64; ++k) acc += sh1[k] * W2[o*64 + k];
      ev[q] = __expf(fmaxf(acc, 0.f));
      ps += ev[q];
    }
    red[t] = ps; __syncthreads();
    for (int s = 128; s > 0; s >>= 1) { if (t < s) red[t] += red[t+s]; __syncthreads(); }
    float inv = 1.f / red[0];
    float* cm = (float*)(wsc + CM_OFF);
    #pragma unroll
    for (int q = 0; q < 4; ++q) cm[b*1024 + q*256 + t] = ev[q] * inv;
  } else {
    int r = bid - 8;
    float* wt = (float*)(wsc + WT_OFF);
    for (int i = r*256 + t; i < 24576; i += 2048) {
      int c = i / 192, slot = i % 192;
      float v;
      if (slot < 64)       v = W_phi[slot*128 + c];
      else if (slot < 128) v = W_theta[(slot-64)*128 + c];
      else                 v = W_rho[(slot-128)*128 + c];
      wt[i] = v;
    }
    if (r == 0 && t < 192) {
      float* bias = (float*)(wsc + BIAS_OFF);
      bias[t] = (t < 64) ? b_phi[t] : (t < 128 ? b_theta[t-64] : b_rho[t-128]);
    }
    if (r == 1) {
      float* se = (float*)(wsc + SUME_OFF);
      for (int i = t; i < 512; i += 256) se[i] = 0.f;
    }
  }
}

// ------------------------------------------------- k1: convs + exp + AB partials
// grid 1024 = 8 b * 128 groups; each block does 2 chunks of 64 positions.
// LDS: Xl[128][68] (8704 f) aliased by aT[64][66]+ecT[64][66] (8448 f);
//      ps[1024] @8704; inv[64] @9728 -> 9792 floats = 39168 B.
__global__ __launch_bounds__(256, 4) void k1_main(const float* __restrict__ x,
                                                  char* __restrict__ wsc) {
  const float* wt   = (const float*)(wsc + WT_OFF);
  const float* bias = (const float*)(wsc + BIAS_OFF);
  const float* cm   = (const float*)(wsc + CM_OFF);
  float* sumE  = (float*)(wsc + SUME_OFF);
  _Float16* e_ws = (_Float16*)(wsc + E_OFF);
  _Float16* v_ws = (_Float16*)(wsc + V_OFF);
  float* part  = (float*)(wsc + PART_OFF);

  int t = threadIdx.x, bid = blockIdx.x;
  int b = bid >> 7, grp = bid & 127;
  int ti = t >> 4, tj = t & 15;
  int o0 = ti*4, p0 = tj*4;
  extern __shared__ float sm[];
  float* Xl  = sm;           // 128*68
  float* aT  = sm;           // 64*66 (aliases Xl)
  float* ecT = sm + 4224;    // 64*66 (aliases Xl)
  float* ps  = sm + 8704;    // 1024
  float* inv = sm + 9728;    // 64
  const float* xb = x + (size_t)b * CC * SB;

  float ab[4][4];
  #pragma unroll
  for (int i = 0; i < 4; ++i)
    #pragma unroll
    for (int j = 0; j < 4; ++j) ab[i][j] = 0.f;

  float bp[4], bt[4], br[4];
  *(float4*)bp = *(const float4*)(bias + o0);
  *(float4*)bt = *(const float4*)(bias + 64 + o0);
  *(float4*)br = *(const float4*)(bias + 128 + o0);

  for (int u = 0; u < 2; ++u) {
    int s0 = (grp*2 + u) * 64;
    __syncthreads();                       // protect Xl/aT/ecT from prev-iter reads
    #pragma unroll
    for (int q = 0; q < 8; ++q) {
      int fid = q*256 + t;
      int c = fid >> 4, p4 = (fid & 15) << 2;
      *(float4*)&Xl[c*68 + p4] = *(const float4*)(xb + c*SB + s0 + p4);
    }
    __syncthreads();

    float a0[4][4], a1[4][4], a2[4][4];
    #pragma unroll
    for (int i = 0; i < 4; ++i)
      #pragma unroll
      for (int j = 0; j < 4; ++j) { a0[i][j] = 0.f; a1[i][j] = 0.f; a2[i][j] = 0.f; }

    #pragma unroll 2
    for (int c = 0; c < CC; ++c) {
      float xr[4], wp[4], wq[4], wr[4];
      *(float4*)xr = *(float4*)&Xl[c*68 + p0];
      *(float4*)wp = *(const float4*)(wt + c*192 + o0);
      *(float4*)wq = *(const float4*)(wt + c*192 + 64 + o0);
      *(float4*)wr = *(const float4*)(wt + c*192 + 128 + o0);
      #pragma unroll
      for (int i = 0; i < 4; ++i)
        #pragma unroll
        for (int j = 0; j < 4; ++j) {
          a0[i][j] += wp[i] * xr[j];
          a1[i][j] += wq[i] * xr[j];
          a2[i][j] += wr[i] * xr[j];
        }
    }

    // bias + exp
    float e[4][4], vx[4][4];
    #pragma unroll
    for (int i = 0; i < 4; ++i)
      #pragma unroll
      for (int j = 0; j < 4; ++j) {
        a0[i][j] += bp[i];
        e[i][j]  = __expf(a1[i][j] + bt[i]);
        vx[i][j] = __expf(a2[i][j] + br[i]);
      }

    // rho channel-softmax: column sums over the 64 channels
    float cs[4];
    #pragma unroll
    for (int j = 0; j < 4; ++j) cs[j] = vx[0][j] + vx[1][j] + vx[2][j] + vx[3][j];
    *(float4*)&ps[ti*64 + p0] = *(float4*)cs;
    __syncthreads();
    if (t < 64) {
      float s = 0.f;
      #pragma unroll
      for (int k = 0; k < 16; ++k) s += ps[k*64 + t];
      inv[t] = 1.f / s;
    }
    __syncthreads();
    float iv[4]; *(float4*)iv = *(float4*)&inv[p0];
    #pragma unroll
    for (int i = 0; i < 4; ++i)
      #pragma unroll
      for (int j = 0; j < 4; ++j) vx[i][j] *= iv[j];

    // store e, V as fp16
    size_t sbase = (size_t)(b*64) * SB + s0 + p0;
    #pragma unroll
    for (int i = 0; i < 4; ++i) {
      half4_t he, hv;
      #pragma unroll
      for (int j = 0; j < 4; ++j) { he[j] = (_Float16)e[i][j]; hv[j] = (_Float16)vx[i][j]; }
      *(half4_t*)(e_ws + sbase + (size_t)(o0+i)*SB) = he;
      *(half4_t*)(v_ws + sbase + (size_t)(o0+i)*SB) = hv;
    }

    // e row-sums (for sumE) into reused ps buffer
    float es[4];
    #pragma unroll
    for (int i = 0; i < 4; ++i) es[i] = e[i][0] + e[i][1] + e[i][2] + e[i][3];
    *(float4*)&ps[tj*64 + o0] = *(float4*)es;

    // Cm weights + transposed tiles for the AB rank-update
    float cmv[4];
    *(float4*)cmv = *(const float4*)(cm + b*1024 + ((s0 + p0) & 1023));
    #pragma unroll
    for (int j = 0; j < 4; ++j) {
      float av[4]  = {a0[0][j], a0[1][j], a0[2][j], a0[3][j]};
      float ev2[4] = {e[0][j]*cmv[j], e[1][j]*cmv[j], e[2][j]*cmv[j], e[3][j]*cmv[j]};
      *(float4*)&aT[(p0+j)*66 + o0]  = *(float4*)av;
      *(float4*)&ecT[(p0+j)*66 + o0] = *(float4*)ev2;
    }
    __syncthreads();
    if (t < 64) {
      float s = 0.f;
      #pragma unroll
      for (int k = 0; k < 16; ++k) s += ps[k*64 + t];
      atomicAdd(&sumE[b*64 + t], s);
    }
    // AB rank-64 update: ab[m][n] += a[m][p] * (e*cm)[n][p]
    #pragma unroll 4
    for (int k = 0; k < 64; ++k) {
      float av[4], ev[4];
      *(float4*)av = *(float4*)&aT[k*66 + o0];
      *(float4*)ev = *(float4*)&ecT[k*66 + p0];
      #pragma unroll
      for (int i = 0; i < 4; ++i)
        #pragma unroll
        for (int j = 0; j < 4; ++j) ab[i][j] += av[i] * ev[j];
    }
  }
  #pragma unroll
  for (int i = 0; i < 4; ++i) {
    float w[4] = {ab[i][0], ab[i][1], ab[i][2], ab[i][3]};
    *(float4*)&part[(size_t)bid*4096 + (o0+i)*64 + p0] = *(float4*)w;
  }
}

// ---------------------------------------------- k2: reduce AB partials, rinv
__global__ void k2_reduce(char* __restrict__ wsc) {
  const float* part = (const float*)(wsc + PART_OFF);
  const float* sumE = (const float*)(wsc + SUME_OFF);
  float* abt  = (float*)(wsc + ABT_OFF);
  float* rinv = (float*)(wsc + RINV_OFF);
  int idx = blockIdx.x * 256 + threadIdx.x;
  int b = idx >> 12, mn = idx & 4095;
  int m = mn >> 6, n = mn & 63;
  const float* p = part + (size_t)b * 128 * 4096 + mn;
  float s = 0.f;
  #pragma unroll 4
  for (int k = 0; k < 128; ++k) s += p[(size_t)k * 4096];
  abt[b*4096 + n*64 + m] = s / sumE[b*64 + n];   // n-major for k3
  if (idx < 512) rinv[idx] = 1.f / sumE[idx];
}

// ---------------------------------------------------------------- k3: Z GEMM
// grid 512 = b(8) * tgroup(4) * hwchunk(16); Z[m][hw] = sum_n ABt[n][m]*V[n][hw]
__global__ __launch_bounds__(256) void k3_z(const char* __restrict__ wsc,
                                            float* __restrict__ zout) {
  const float* abt = (const float*)(wsc + ABT_OFF);
  const _Float16* v_ws = (const _Float16*)(wsc + V_OFF);
  __shared__ float ABl[64*66];
  __shared__ float Vl[64*68];
  int t = threadIdx.x, bid = blockIdx.x;
  int b = bid >> 6, tg = (bid >> 4) & 3, hwc = bid & 15;
  #pragma unroll
  for (int q = 0; q < 16; ++q) {
    int fid = q*256 + t;
    ABl[(fid >> 6)*66 + (fid & 63)] = abt[b*4096 + fid];
  }
  int ti = t >> 4, tj = t & 15;
  int m0 = ti*4, h0 = tj*4;
  for (int ts = 0; ts < 4; ++ts) {
    int tt = tg*4 + ts;
    size_t sbase = (size_t)tt*1024 + hwc*64;
    __syncthreads();   // covers ABl staging (first iter) + Vl reuse
    #pragma unroll
    for (int q = 0; q < 4; ++q) {
      int fid = q*256 + t;
      int n = fid >> 4, h4 = (fid & 15) << 2;
      half4_t hv = *(const half4_t*)(v_ws + (size_t)(b*64+n)*SB + sbase + h4);
      Vl[n*68 + h4 + 0] = (float)hv[0];
      Vl[n*68 + h4 + 1] = (float)hv[1];
      Vl[n*68 + h4 + 2] = (float)hv[2];
      Vl[n*68 + h4 + 3] = (float)hv[3];
    }
    __syncthreads();
    float acc[4][4];
    #pragma unroll
    for (int i = 0; i < 4; ++i)
      #pragma unroll
      for (int j = 0; j < 4; ++j) acc[i][j] = 0.f;
    #pragma unroll 4
    for (int k = 0; k < 64; ++k) {
      float av[4], vv[4];
      *(float4*)av = *(float4*)&ABl[k*66 + m0];
      *(float4*)vv = *(float4*)&Vl[k*68 + h0];
      #pragma unroll
      for (int i = 0; i < 4; ++i)
        #pragma unroll
        for (int j = 0; j < 4; ++j) acc[i][j] += av[i] * vv[j];
    }
    #pragma unroll
    for (int i = 0; i < 4; ++i) {
      float w[4] = {acc[i][0], acc[i][1], acc[i][2], acc[i][3]};
      *(float4*)(zout + (size_t)(b*64 + m0 + i)*SB + sbase + h0) = *(float4*)w;
    }
  }
}

// --------------------------------------------------- k4: attn = e*V/sumE, transposed
// grid 1024 = b(8) * n(64) * half(2); thread owns 2 hw, 16 t values each.
__global__ void k4_attn(const char* __restrict__ wsc, float* __restrict__ out) {
  const _Float16* e_ws = (const _Float16*)(wsc + E_OFF);
  const _Float16* v_ws = (const _Float16*)(wsc + V_OFF);
  const float* rinv = (const float*)(wsc + RINV_OFF);
  int t = threadIdx.x, bid = blockIdx.x;
  int b = bid >> 7, r = bid & 127;
  int n = r >> 1;
  int hw0 = (r & 1)*512 + t*2;
  float ri = rinv[b*64 + n];
  size_t ibase = (size_t)(b*64 + n)*SB + hw0;
  float tv[16][2];
  #pragma unroll
  for (int k = 0; k < 16; ++k) {
    half2_t e2 = *(const half2_t*)(e_ws + ibase + k*1024);
    half2_t v2 = *(const half2_t*)(v_ws + ibase + k*1024);
    tv[k][0] = (float)e2[0] * (float)v2[0] * ri;
    tv[k][1] = (float)e2[1] * (float)v2[1] * ri;
  }
  float* ob = out + 8388608 + ((size_t)(b*64 + n)*1024 + hw0)*16;
  #pragma unroll
  for (int h = 0; h < 2; ++h)
    #pragma unroll
    for (int q = 0; q < 4; ++q) {
      float w[4] = {tv[q*4+0][h], tv[q*4+1][h], tv[q*4+2][h], tv[q*4+3][h]};
      *(float4*)(ob + h*16 + q*4) = *(float4*)w;
    }
}

extern "C" void kernel_launch(void* const* d_in, const int* in_sizes, int n_in,
                              void* d_out, int out_size, void* d_ws, size_t ws_size,
                              hipStream_t stream) {
  const float* input   = (const float*)d_in[0];
  const float* cond    = (const float*)d_in[1];
  const float* W_phi   = (const float*)d_in[2];
  const float* b_phi   = (const float*)d_in[3];
  const float* W_theta = (const float*)d_in[4];
  const float* b_theta = (const float*)d_in[5];
  const float* W_rho   = (const float*)d_in[6];
  const float* b_rho   = (const float*)d_in[7];
  const float* W1      = (const float*)d_in[8];
  const float* b1      = (const float*)d_in[9];
  const float* W2      = (const float*)d_in[10];
  const float* b2      = (const float*)d_in[11];
  char* wsc = (char*)d_ws;
  float* out = (float*)d_out;

  hipLaunchKernelGGL(k0_setup, dim3(16), dim3(256), 0, stream,
                     cond, W_phi, b_phi, W_theta, b_theta, W_rho, b_rho,
                     W1, b1, W2, b2, wsc);
  hipLaunchKernelGGL(k1_main, dim3(1024), dim3(256), 39168, stream, input, wsc);
  hipLaunchKernelGGL(k2_reduce, dim3(128), dim3(256), 0, stream, wsc);
  hipLaunchKernelGGL(k3_z, dim3(512), dim3(256), 0, stream, wsc, out);
  hipLaunchKernelGGL(k4_attn, dim3(1024), dim3(256), 0, stream, wsc, out);
}